// Round 3
// baseline (2795.189 us; speedup 1.0000x reference)
//
#include <hip/hip_runtime.h>
#include <stdint.h>

#define Hn 512
#define Dn 128
#define Nn 64
#define Tn 512
#define NT (Nn*Tn)   // 32768

typedef unsigned int uint;
typedef unsigned short ushort;
typedef unsigned long long u64;

typedef __attribute__((ext_vector_type(4))) float f32x4;
typedef __attribute__((ext_vector_type(8))) short s16x8;

#define POISON 0xFFC1FFC1FFC1FFC1ULL   // 4x bf16 negative-NaN; data is never NaN

// ---------- ws layout (bytes) ----------
// emitb : 0x0000000  NT*Hn*2  = 32 MB
// rm    : 0x2000000  NT*4     = 128 KB
// wmat  : 0x2020000  Hn*Dn*4  = 256 KB
// bias  : 0x2060000  Hn*4     = 2 KB
// pt    : 0x2060800  Hn*Hn*2  = 512 KB
// abuf  : 0x20E0800  2 bufs * 4 grp * 8 consumers * 8 producers * 264 u64 = 1,081,344 B
//         mailbox chunk layout: 0..255 data (seq s=c>>4, 4 cols), 256..259 per-seq bf16 partial max

__device__ inline float bf2f(ushort u) { union { uint i; float f; } v; v.i = uint(u) << 16; return v.f; }
__device__ inline ushort f2bf(float f) {
  union { uint i; float f; } v; v.f = f;
  uint u = v.i;
  uint r = (u + 0x7FFFu + ((u >> 16) & 1u)) >> 16;
  return ushort(r);
}

__device__ inline u64 a64(const u64* p) {
  return __hip_atomic_load(p, __ATOMIC_RELAXED, __HIP_MEMORY_SCOPE_AGENT);
}
__device__ inline void s64(u64* p, u64 v) {
  __hip_atomic_store(p, v, __ATOMIC_RELAXED, __HIP_MEMORY_SCOPE_AGENT);
}

__global__ void k_zero(u64* ab) {          // poison entire mailbox region (every launch)
  ab[(size_t)blockIdx.x * 256 + threadIdx.x] = POISON;
}

__global__ void k_prep(const float* __restrict__ py, float* __restrict__ wmat, float* __restrict__ bias) {
  int h = blockIdx.x;
  int d = threadIdx.x;
  float p = py[h * Dn + d];
  float lp = logf(p);
  float l1 = log1pf(-p);
  wmat[h * Dn + d] = lp - l1;
  float v = l1;
  for (int o = 1; o < 64; o <<= 1) v += __shfl_xor(v, o, 64);
  __shared__ float s2[2];
  if ((threadIdx.x & 63) == 0) s2[threadIdx.x >> 6] = v;
  __syncthreads();
  if (threadIdx.x == 0) bias[h] = s2[0] + s2[1];
}

__global__ void k_pt(const float* __restrict__ px, ushort* __restrict__ pt) {
  __shared__ ushort sh[32][33];
  int tx = threadIdx.x, ty = threadIdx.y;
  sh[ty][tx] = f2bf(px[(blockIdx.y * 32 + ty) * Hn + blockIdx.x * 32 + tx]);
  __syncthreads();
  pt[(blockIdx.x * 32 + ty) * Hn + blockIdx.y * 32 + tx] = sh[tx][ty];
}

__global__ __launch_bounds__(256) void k_emit(const float* __restrict__ A, const float* __restrict__ wmat,
                                              const float* __restrict__ bias, ushort* __restrict__ eb) {
  __shared__ float As[Dn][64];
  __shared__ float Bs[Dn][64];
  int t = threadIdx.x;
  int r0 = blockIdx.y * 64, h0 = blockIdx.x * 64;
  int row = t >> 2, q = t & 3;
  for (int i = 0; i < 8; i++) {
    int ch = q + i * 4;
    float4 a = *(const float4*)(A + (size_t)(r0 + row) * Dn + ch * 4);
    As[ch * 4 + 0][row] = a.x; As[ch * 4 + 1][row] = a.y;
    As[ch * 4 + 2][row] = a.z; As[ch * 4 + 3][row] = a.w;
    float4 b = *(const float4*)(wmat + (size_t)(h0 + row) * Dn + ch * 4);
    Bs[ch * 4 + 0][row] = b.x; Bs[ch * 4 + 1][row] = b.y;
    Bs[ch * 4 + 2][row] = b.z; Bs[ch * 4 + 3][row] = b.w;
  }
  __syncthreads();
  int tx = t & 15, ty = t >> 4;
  float acc[4][4] = {};
  for (int k = 0; k < Dn; k++) {
    float av[4], bv[4];
    *(float4*)av = *(const float4*)&As[k][ty * 4];
    *(float4*)bv = *(const float4*)&Bs[k][tx * 4];
#pragma unroll
    for (int ii = 0; ii < 4; ii++)
#pragma unroll
      for (int jj = 0; jj < 4; jj++) acc[ii][jj] += av[ii] * bv[jj];
  }
  float bsv[4];
  *(float4*)bsv = *(const float4*)(bias + h0 + tx * 4);
#pragma unroll
  for (int ii = 0; ii < 4; ii++) {
    int r = r0 + ty * 4 + ii;
    ushort4 u;
    u.x = f2bf(acc[ii][0] + bsv[0]); u.y = f2bf(acc[ii][1] + bsv[1]);
    u.z = f2bf(acc[ii][2] + bsv[2]); u.w = f2bf(acc[ii][3] + bsv[3]);
    *(ushort4*)(eb + (size_t)r * Hn + h0 + tx * 4) = u;
  }
}

__global__ void k_rowmax(const ushort* __restrict__ eb, float* __restrict__ rm) {
  int r = blockIdx.x, lane = threadIdx.x;
  uint4 u = *(const uint4*)(eb + (size_t)r * Hn + lane * 8);
  float m = bf2f(ushort(u.x & 0xffff));
  m = fmaxf(m, bf2f(ushort(u.x >> 16)));
  m = fmaxf(m, bf2f(ushort(u.y & 0xffff))); m = fmaxf(m, bf2f(ushort(u.y >> 16)));
  m = fmaxf(m, bf2f(ushort(u.z & 0xffff))); m = fmaxf(m, bf2f(ushort(u.z >> 16)));
  m = fmaxf(m, bf2f(ushort(u.w & 0xffff))); m = fmaxf(m, bf2f(ushort(u.w >> 16)));
  for (int o = 1; o < 64; o <<= 1) m = fmaxf(m, __shfl_xor(m, o, 64));
  if (lane == 0) rm[r] = m;
}

__global__ void k_bexp(ushort* __restrict__ eb, const float* __restrict__ rm) {
  int i = blockIdx.x * 256 + threadIdx.x;
  uint* p = (uint*)eb;
  uint u = p[i];
  float m = rm[i >> 8];
  float f0 = expf(bf2f(ushort(u & 0xffff)) - m);
  float f1 = expf(bf2f(ushort(u >> 16)) - m);
  p[i] = uint(f2bf(f0)) | (uint(f2bf(f1)) << 16);
}

// 32 WGs = 4 seq-groups x 8 col-groups (64 cols), 256 thr. Data-as-flag mailbox protocol:
// producer fires 8 copies of its slice (+bf16 per-seq partial max), consumers poll own
// mailboxes for !=POISON, re-poison after read (acked by pre-store vmcnt(0)).
__global__ __launch_bounds__(256) void k_rec(
    const ushort* __restrict__ eb, const float* __restrict__ rm,
    const ushort* __restrict__ pt, const float* __restrict__ px,
    const int* __restrict__ lens, u64* __restrict__ abuf64,
    float* __restrict__ outp) {
  const int bid = blockIdx.x;
  const int grp = bid >> 3;   // 0..3
  const int g = bid & 7;      // 0..7
  const int t = threadIdx.x;  // 0..255
  const int lane = t & 63, wv = t >> 6;

  __shared__ ushort Pf[4096 * 8];    // 64 KB B-frags
  __shared__ ushort Al[16][520];     // alpha rows bf16 (+8 pad)
  __shared__ float bl[16][64];       // B values this step (fp32 scratch at init)
  __shared__ ushort outs[16][64];    // output staging
  __shared__ float sm[16][4];        // per-seq per-wave slice max
  __shared__ ushort pmx[2][8][16];   // received partial maxima, parity-buffered
  __shared__ ushort pmrow[16];
  __shared__ float Cacc[16], fsum[16];
  __shared__ int lenl[16];

  if (t < 16) {
    lenl[t] = lens[grp * 16 + t];
    Cacc[t] = rm[(grp * 16 + t) * Tn];
  }
  // stage P-slice into B-frag layout: cols [g*64, g*64+64)
  for (int i = 0; i < 16; i++) {
    int f = i * 256 + t;
    int kt = f >> 8, nt = (f >> 6) & 3, ln = f & 63;
    int c = g * 64 + nt * 16 + (ln & 15);
    int k0 = kt * 32 + (ln >> 4) * 8;
    uint4 v = *(const uint4*)(pt + (size_t)c * Hn + k0);
    *(uint4*)(&Pf[f * 8]) = v;
  }
  // init alpha (t=0): raw0 = px[0][h] * B[n][0][h]; bl[][] doubles as fp32 stage
  {
    int s = t >> 4, c4 = (t & 15) * 4;
    int h = g * 64 + c4;
    float4 p4 = *(const float4*)(px + h);
    ushort4 b4 = *(const ushort4*)(eb + (size_t)(grp * 16 + s) * Tn * Hn + h);
    float v0 = p4.x * bf2f(b4.x), v1 = p4.y * bf2f(b4.y);
    float v2 = p4.z * bf2f(b4.z), v3 = p4.w * bf2f(b4.w);
    bl[s][c4 + 0] = v0; bl[s][c4 + 1] = v1; bl[s][c4 + 2] = v2; bl[s][c4 + 3] = v3;
    outs[s][c4 + 0] = f2bf(v0); outs[s][c4 + 1] = f2bf(v1);
    outs[s][c4 + 2] = f2bf(v2); outs[s][c4 + 3] = f2bf(v3);
  }
  __syncthreads();
  if (t < 16) {
    float m = bl[t][0];
    for (int c = 1; c < 64; c++) m = fmaxf(m, bl[t][c]);
    pmrow[t] = f2bf(m);
  }
  __syncthreads();
  {  // init mailbox stores, buf 0
    u64 v = *(u64*)(&outs[t >> 4][(t & 15) * 4]);
#pragma unroll
    for (int c = 0; c < 8; c++)
      s64(abuf64 + (size_t)(((grp * 8 + c) * 8 + g) * 264 + t), v);
    if (t < 4) {
      ushort4 pk = *(ushort4*)(&pmrow[t * 4]);
      u64 pv = *(u64*)&pk;
#pragma unroll
      for (int c = 0; c < 8; c++)
        s64(abuf64 + (size_t)(((grp * 8 + c) * 8 + g) * 264 + 256 + t), pv);
    }
  }
  const int t_end = lenl[15];  // lengths sorted -> group max
  // prefetch B-slice for ts=1
  ushort4 bpre;
  {
    int s = t >> 4, c4 = (t & 15) * 4;
    bpre = *(const ushort4*)(eb + ((size_t)(grp * 16 + s) * Tn + 1) * Hn + g * 64 + c4);
  }

  for (int ts = 1; ts < t_end; ts++) {
    const int rb = (ts + 1) & 1, wb = ts & 1, par = rb;
    // ---- poll mailboxes (data is the flag) ----
    u64* ap[8];
    u64 vdat[8];
#pragma unroll
    for (int p = 0; p < 8; p++)
      ap[p] = abuf64 + (size_t)((((rb * 4 + grp) * 8 + g) * 8 + p) * 264 + t);
    u64* app = nullptr;
    u64 vpm = 0;
    if (t < 32)
      app = abuf64 + (size_t)((((rb * 4 + grp) * 8 + g) * 8 + (t >> 2)) * 264 + 256 + (t & 3));
    {
      uint pend = (t < 32) ? 0x1ffu : 0xffu;
      while (pend) {
#pragma unroll
        for (int p = 0; p < 8; p++)
          if (pend & (1u << p)) {
            u64 v = a64(ap[p]);
            if (v != POISON) { vdat[p] = v; pend &= ~(1u << p); }
          }
        if (pend & 0x100u) {
          u64 v = a64(app);
          if (v != POISON) { vpm = v; pend &= ~0x100u; }
        }
      }
    }
    {
      int s = t >> 4, q4 = (t & 15) * 4;
#pragma unroll
      for (int p = 0; p < 8; p++) *(u64*)(&Al[s][p * 64 + q4]) = vdat[p];
#pragma unroll
      for (int p = 0; p < 8; p++) s64(ap[p], POISON);
      if (t < 32) { *(u64*)(&pmx[par][t >> 2][(t & 3) * 4]) = vpm; s64(app, POISON); }
    }
    // stage this step's B values; prefetch next
    {
      int s4 = t >> 4, c4 = (t & 15) * 4;
      bl[s4][c4 + 0] = bf2f(bpre.x); bl[s4][c4 + 1] = bf2f(bpre.y);
      bl[s4][c4 + 2] = bf2f(bpre.z); bl[s4][c4 + 3] = bf2f(bpre.w);
      int tn2 = (ts + 1 < Tn) ? ts + 1 : Tn - 1;
      bpre = *(const ushort4*)(eb + ((size_t)(grp * 16 + s4) * Tn + tn2) * Hn + g * 64 + c4);
    }
    __syncthreads();   // (A) Al/pmx/bl visible
    // ---- MFMA: two independent 8-deep chains ----
    f32x4 acc0 = {0.f, 0.f, 0.f, 0.f}, acc1 = {0.f, 0.f, 0.f, 0.f};
    {
      int s_m = lane & 15, quad = lane >> 4;
#pragma unroll
      for (int kt = 0; kt < 8; kt++) {
        uint4 av = *(const uint4*)(&Al[s_m][kt * 32 + quad * 8]);
        uint4 bv = *(const uint4*)(&Pf[((kt * 4 + wv) * 64 + lane) * 8]);
        acc0 = __builtin_amdgcn_mfma_f32_16x16x32_bf16(
            __builtin_bit_cast(s16x8, av), __builtin_bit_cast(s16x8, bv), acc0, 0, 0, 0);
      }
#pragma unroll
      for (int kt = 8; kt < 16; kt++) {
        uint4 av = *(const uint4*)(&Al[s_m][kt * 32 + quad * 8]);
        uint4 bv = *(const uint4*)(&Pf[((kt * 4 + wv) * 64 + lane) * 8]);
        acc1 = __builtin_amdgcn_mfma_f32_16x16x32_bf16(
            __builtin_bit_cast(s16x8, av), __builtin_bit_cast(s16x8, bv), acc1, 0, 0, 0);
      }
    }
    // ---- epilogue: per-lane redundant m from partials, scale, freeze, slice-max ----
    {
      int cl = wv * 16 + (lane & 15);
      int quad = lane >> 4;
      float mr[4] = {-1.f, -1.f, -1.f, -1.f};
#pragma unroll
      for (int p = 0; p < 8; p++) {
        u64 du = *(const u64*)(&pmx[par][p][quad * 4]);
#pragma unroll
        for (int r = 0; r < 4; r++)
          mr[r] = fmaxf(mr[r], bf2f(ushort((du >> (16 * r)) & 0xffff)));
      }
      float vv[4];
#pragma unroll
      for (int r = 0; r < 4; r++) {
        int s = quad * 4 + r;
        float v = (acc0[r] + acc1[r]) * bl[s][cl] * (1.0f / mr[r]);
        if (ts >= lenl[s]) v = bf2f(Al[s][g * 64 + cl]);
        vv[r] = v;
        outs[s][cl] = f2bf(v);
      }
#pragma unroll
      for (int r = 0; r < 4; r++) {
        float mm = vv[r];
        mm = fmaxf(mm, __shfl_xor(mm, 1, 64));
        mm = fmaxf(mm, __shfl_xor(mm, 2, 64));
        mm = fmaxf(mm, __shfl_xor(mm, 4, 64));
        mm = fmaxf(mm, __shfl_xor(mm, 8, 64));
        if ((lane & 15) == 0) sm[quad * 4 + r][wv] = mm;
      }
    }
    __syncthreads();   // (B) outs/sm complete; all Al/pmx/bl reads done
    asm volatile("s_waitcnt vmcnt(0)" ::: "memory");   // poisons durable before new data
    // ---- mailbox stores (fire-and-forget) ----
    {
      u64 v = *(u64*)(&outs[t >> 4][(t & 15) * 4]);
#pragma unroll
      for (int c = 0; c < 8; c++)
        s64(abuf64 + (size_t)((((wb * 4 + grp) * 8 + c) * 8 + g) * 264 + t), v);
      if (t < 4) {
        ushort4 pk;
#pragma unroll
        for (int j = 0; j < 4; j++) {
          int s = t * 4 + j;
          pk[j] = f2bf(fmaxf(fmaxf(sm[s][0], sm[s][1]), fmaxf(sm[s][2], sm[s][3])));
        }
        u64 pv = *(u64*)&pk;
#pragma unroll
        for (int c = 0; c < 8; c++)
          s64(abuf64 + (size_t)((((wb * 4 + grp) * 8 + c) * 8 + g) * 264 + 256 + t), pv);
      }
    }
    // ---- off-critical-path: Cacc (g==0 only) ----
    if (g == 0 && t < 16 && ts < lenl[t]) {
      float m = bf2f(pmx[par][0][t]);
#pragma unroll
      for (int p = 1; p < 8; p++) m = fmaxf(m, bf2f(pmx[par][p][t]));
      Cacc[t] += logf(m) + rm[(grp * 16 + t) * Tn + ts];
    }
  }

  // ---- finalize (g==0): poll final buffer, out[n] = Cacc + log(sum_h raw_final) ----
  if (g == 0) {
    const int fb = (t_end - 1) & 1;
    u64* ap[8];
    u64 vdat[8];
#pragma unroll
    for (int p = 0; p < 8; p++)
      ap[p] = abuf64 + (size_t)((((fb * 4 + grp) * 8 + 0) * 8 + p) * 264 + t);
    uint pend = 0xffu;
    while (pend) {
#pragma unroll
      for (int p = 0; p < 8; p++)
        if (pend & (1u << p)) {
          u64 v = a64(ap[p]);
          if (v != POISON) { vdat[p] = v; pend &= ~(1u << p); }
        }
    }
    float a = 0.f;
#pragma unroll
    for (int p = 0; p < 8; p++) {
      u64 v = vdat[p];
      a += bf2f(ushort(v & 0xffff)) + bf2f(ushort((v >> 16) & 0xffff))
         + bf2f(ushort((v >> 32) & 0xffff)) + bf2f(ushort((v >> 48) & 0xffff));
    }
    a += __shfl_xor(a, 1, 64); a += __shfl_xor(a, 2, 64);
    a += __shfl_xor(a, 4, 64); a += __shfl_xor(a, 8, 64);
    if ((lane & 15) == 0) fsum[(t >> 4)] = a;
    __syncthreads();
    if (t < 16) outp[grp * 16 + t] = Cacc[t] + logf(fsum[t]);
  }
}

extern "C" void kernel_launch(void* const* d_in, const int* in_sizes, int n_in,
                              void* d_out, int out_size, void* d_ws, size_t ws_size,
                              hipStream_t stream) {
  const float* seq = (const float*)d_in[0];
  const int* lens = (const int*)d_in[1];
  const float* px = (const float*)d_in[2];
  const float* py = (const float*)d_in[3];
  char* ws = (char*)d_ws;
  ushort* emitb = (ushort*)(ws + 0x0000000);
  float* rm     = (float*)(ws + 0x2000000);
  float* wmat   = (float*)(ws + 0x2020000);
  float* bias   = (float*)(ws + 0x2060000);
  ushort* pt    = (ushort*)(ws + 0x2060800);
  u64* abuf64   = (u64*)(ws + 0x20E0800);
  float* outp   = (float*)d_out;

  hipLaunchKernelGGL(k_prep, dim3(512), dim3(128), 0, stream, py, wmat, bias);
  hipLaunchKernelGGL(k_pt, dim3(16, 16), dim3(32, 32), 0, stream, px, pt);
  hipLaunchKernelGGL(k_emit, dim3(8, 512), dim3(256), 0, stream, seq, wmat, bias, emitb);
  hipLaunchKernelGGL(k_rowmax, dim3(NT), dim3(64), 0, stream, emitb, rm);
  hipLaunchKernelGGL(k_bexp, dim3(NT), dim3(256), 0, stream, emitb, rm);
  hipLaunchKernelGGL(k_zero, dim3(528), dim3(256), 0, stream, abuf64);  // re-poison every launch
  hipLaunchKernelGGL(k_rec, dim3(32), dim3(256), 0, stream, emitb, rm, pt, px, lens, abuf64, outp);
}

// Round 4
// 1377.223 us; speedup vs baseline: 2.0296x; 2.0296x over previous
//
#include <hip/hip_runtime.h>
#include <stdint.h>

#define Hn 512
#define Dn 128
#define Nn 64
#define Tn 512
#define NT (Nn*Tn)   // 32768

typedef unsigned int uint;
typedef unsigned short ushort;
typedef unsigned long long u64;

typedef __attribute__((ext_vector_type(4))) float f32x4;

#define POISON 0xFFFFFFFFFFFFFFFFULL  // u64 of fp8 data bytes (<=0x7F each) can never be this; fp32 scales never NaN

// ---------- ws layout (bytes) ----------
// emitb : 0x0000000  NT*Hn*2  = 32 MB   (exp(emit-rowmax), bf16)
// rm    : 0x2000000  NT*4     = 128 KB
// wmat  : 0x2020000  Hn*Dn*4  = 256 KB
// bias  : 0x2060000  Hn*4     = 2 KB
// cs    : 0x2061000  Hn*4     (448/colmax of P)
// rcsg  : 0x2062000  Hn*4     (colmax/448)
// pq    : 0x2070000  2*16*16*64*8 = 256 KB (P fp8 e4m3, MFMA B-frag order [half][ktg][ntl][lane])
// mb    : 0x20B0000  16 boxes * 520 u64 = 66.5 KB (alpha mailboxes [grp][sender][parity])

__device__ inline float bf2f(ushort u) { union { uint i; float f; } v; v.i = uint(u) << 16; return v.f; }
__device__ inline ushort f2bf(float f) {
  union { uint i; float f; } v; v.f = f;
  uint u = v.i;
  uint r = (u + 0x7FFFu + ((u >> 16) & 1u)) >> 16;
  return ushort(r);
}
__device__ inline u64 a64(const u64* p) {
  return __hip_atomic_load(p, __ATOMIC_RELAXED, __HIP_MEMORY_SCOPE_AGENT);
}
__device__ inline void s64(u64* p, u64 v) {
  __hip_atomic_store(p, v, __ATOMIC_RELAXED, __HIP_MEMORY_SCOPE_AGENT);
}
// e4m3fn decode (non-negative only); used in finale only
__device__ inline float fp8val(uint b) {
  uint e = (b >> 3) & 15u, m = b & 7u;
  return e ? ldexpf((float)(8u + m), (int)e - 10) : ldexpf((float)m, -9);
}
// pack 8 floats (k-ascending) to 8 e4m3 bytes; SAME helper packs A and B frags,
// so any HW k-permutation within the 32-k tile cancels between operands.
__device__ inline u64 pack8fp8(const float* v, float qs) {
  int lo = 0, hi = 0;
  lo = __builtin_amdgcn_cvt_pk_fp8_f32(v[0] * qs, v[1] * qs, lo, false);
  lo = __builtin_amdgcn_cvt_pk_fp8_f32(v[2] * qs, v[3] * qs, lo, true);
  hi = __builtin_amdgcn_cvt_pk_fp8_f32(v[4] * qs, v[5] * qs, hi, false);
  hi = __builtin_amdgcn_cvt_pk_fp8_f32(v[6] * qs, v[7] * qs, hi, true);
  return (u64)(uint)lo | ((u64)(uint)hi << 32);
}

__global__ void k_zero(u64* mb) {
  int i = blockIdx.x * 256 + threadIdx.x;
  if (i < 16 * 520) mb[i] = POISON;
}

__global__ void k_prep(const float* __restrict__ py, float* __restrict__ wmat, float* __restrict__ bias) {
  int h = blockIdx.x, d = threadIdx.x;
  float p = py[h * Dn + d];
  float lp = logf(p), l1 = log1pf(-p);
  wmat[h * Dn + d] = lp - l1;
  float v = l1;
  for (int o = 1; o < 64; o <<= 1) v += __shfl_xor(v, o, 64);
  __shared__ float s2[2];
  if ((threadIdx.x & 63) == 0) s2[threadIdx.x >> 6] = v;
  __syncthreads();
  if (threadIdx.x == 0) bias[h] = s2[0] + s2[1];
}

// per-column max of P -> cs = 448/max, rcsg = max/448
__global__ void k_cs(const float* __restrict__ px, float* __restrict__ cs, float* __restrict__ rcsg) {
  int j = threadIdx.x;  // 512 threads
  float m = 0.f;
#pragma unroll 8
  for (int k = 0; k < Hn; k++) m = fmaxf(m, px[(size_t)k * Hn + j]);
  cs[j] = 448.0f / m;
  rcsg[j] = m * (1.0f / 448.0f);
}

// quantize P (col-scaled) into MFMA B-frag order: pq[((g*16+kt)*16+ntl)*64+lane] (8 bytes k-ascending)
__global__ __launch_bounds__(256) void k_pq(const float* __restrict__ px, const float* __restrict__ cs,
                                            u64* __restrict__ pq) {
  __shared__ float ksl[32][260];
  int g = blockIdx.x & 1, kt = blockIdx.x >> 1;  // kt = global k-tile 0..15
  int t = threadIdx.x;
  int k0 = kt * 32;
  for (int i = 0; i < 8; i++) {
    int q = i * 256 + t;          // float4 id over 32x64
    int row = q >> 6, c4 = q & 63;
    float4 v = *(const float4*)(px + (size_t)(k0 + row) * Hn + g * 256 + c4 * 4);
    ksl[row][c4 * 4 + 0] = v.x; ksl[row][c4 * 4 + 1] = v.y;
    ksl[row][c4 * 4 + 2] = v.z; ksl[row][c4 * 4 + 3] = v.w;
  }
  __syncthreads();
  for (int i = 0; i < 4; i++) {
    int fid = i * 256 + t;        // (ntl, lane)
    int ntl = fid >> 6, l = fid & 63;
    int col = ntl * 16 + (l & 15);
    int kr0 = (l >> 4) * 8;
    float csv = cs[g * 256 + col];
    float vv[8];
#pragma unroll
    for (int j = 0; j < 8; j++) vv[j] = ksl[kr0 + j][col];
    pq[(size_t)(((g * 16 + kt) * 16 + ntl) * 64 + l)] = pack8fp8(vv, csv);
  }
}

__global__ __launch_bounds__(256) void k_emit(const float* __restrict__ A, const float* __restrict__ wmat,
                                              const float* __restrict__ bias, ushort* __restrict__ eb) {
  __shared__ float As[Dn][64];
  __shared__ float Bs[Dn][64];
  int t = threadIdx.x;
  int r0 = blockIdx.y * 64, h0 = blockIdx.x * 64;
  int row = t >> 2, q = t & 3;
  for (int i = 0; i < 8; i++) {
    int ch = q + i * 4;
    float4 a = *(const float4*)(A + (size_t)(r0 + row) * Dn + ch * 4);
    As[ch * 4 + 0][row] = a.x; As[ch * 4 + 1][row] = a.y;
    As[ch * 4 + 2][row] = a.z; As[ch * 4 + 3][row] = a.w;
    float4 b = *(const float4*)(wmat + (size_t)(h0 + row) * Dn + ch * 4);
    Bs[ch * 4 + 0][row] = b.x; Bs[ch * 4 + 1][row] = b.y;
    Bs[ch * 4 + 2][row] = b.z; Bs[ch * 4 + 3][row] = b.w;
  }
  __syncthreads();
  int tx = t & 15, ty = t >> 4;
  float acc[4][4] = {};
  for (int k = 0; k < Dn; k++) {
    float av[4], bv[4];
    *(float4*)av = *(const float4*)&As[k][ty * 4];
    *(float4*)bv = *(const float4*)&Bs[k][tx * 4];
#pragma unroll
    for (int ii = 0; ii < 4; ii++)
#pragma unroll
      for (int jj = 0; jj < 4; jj++) acc[ii][jj] += av[ii] * bv[jj];
  }
  float bsv[4];
  *(float4*)bsv = *(const float4*)(bias + h0 + tx * 4);
#pragma unroll
  for (int ii = 0; ii < 4; ii++) {
    int r = r0 + ty * 4 + ii;
    ushort4 u;
    u.x = f2bf(acc[ii][0] + bsv[0]); u.y = f2bf(acc[ii][1] + bsv[1]);
    u.z = f2bf(acc[ii][2] + bsv[2]); u.w = f2bf(acc[ii][3] + bsv[3]);
    *(ushort4*)(eb + (size_t)r * Hn + h0 + tx * 4) = u;
  }
}

__global__ void k_rowmax(const ushort* __restrict__ eb, float* __restrict__ rm) {
  int r = blockIdx.x, lane = threadIdx.x;
  uint4 u = *(const uint4*)(eb + (size_t)r * Hn + lane * 8);
  float m = bf2f(ushort(u.x & 0xffff));
  m = fmaxf(m, bf2f(ushort(u.x >> 16)));
  m = fmaxf(m, bf2f(ushort(u.y & 0xffff))); m = fmaxf(m, bf2f(ushort(u.y >> 16)));
  m = fmaxf(m, bf2f(ushort(u.z & 0xffff))); m = fmaxf(m, bf2f(ushort(u.z >> 16)));
  m = fmaxf(m, bf2f(ushort(u.w & 0xffff))); m = fmaxf(m, bf2f(ushort(u.w >> 16)));
  for (int o = 1; o < 64; o <<= 1) m = fmaxf(m, __shfl_xor(m, o, 64));
  if (lane == 0) rm[r] = m;
}

__global__ void k_bexp(ushort* __restrict__ eb, const float* __restrict__ rm) {
  int i = blockIdx.x * 256 + threadIdx.x;
  uint* p = (uint*)eb;
  uint u = p[i];
  float m = rm[i >> 8];
  float f0 = expf(bf2f(ushort(u & 0xffff)) - m);
  float f1 = expf(bf2f(ushort(u >> 16)) - m);
  p[i] = uint(f2bf(f0)) | (uint(f2bf(f1)) << 16);
}

// 8 WGs = 4 seq-groups x 2 halves (256 cols each), 512 threads, ~154 KB LDS.
// fp8 alpha + fp8 P; single-partner data-as-flag exchange (poison protocol).
__global__ __launch_bounds__(512) void k_rec2(
    const ushort* __restrict__ eb, const float* __restrict__ rm,
    const u64* __restrict__ pq, const float* __restrict__ px,
    const float* __restrict__ rcsg, const int* __restrict__ lens,
    u64* __restrict__ mb, float* __restrict__ outp) {
  const int grp = blockIdx.x >> 1;   // 0..3
  const int hh = blockIdx.x & 1;     // 0..1 (column half)
  const int t = threadIdx.x;         // 0..511
  const int w = t >> 6, lane = t & 63, quad = (t >> 4) & 3, l15 = t & 15;

  __shared__ u64 PfL[16384];       // 128 KB: P fp8 B-frags [ktg 0..15][ntl 0..15][lane]
  __shared__ u64 AownL[512];       // own alpha-half A-frags [kt_rel 0..7][lane]
  __shared__ u64 ApeerL[512];      // peer alpha-half A-frags
  __shared__ float ut[16][260];    // u values (own cols), fp32
  __shared__ float rcsL[256];
  __shared__ float moS[16], mpS[16], rqsS[16], CaccS[16];
  __shared__ float sredO[8][16], sredP[8][16];
  __shared__ int lenl[16];

  // ---- one-time staging ----
  for (int i = 0; i < 32; i++) PfL[i * 512 + t] = pq[(size_t)hh * 16384 + i * 512 + t];
  if (t < 256) rcsL[t] = rcsg[hh * 256 + t];
  if (t < 16) {
    lenl[t] = lens[grp * 16 + t];
    if (hh == 0) CaccS[t] = rm[(size_t)(grp * 16 + t) * Tn];
  }
  const int gcb = hh * 256;  // global col base of own half

  // ---- init: v0 = px[0][j] * eb[n][0][j] over own cols ----
  {
    int s = t >> 5, c8 = (t & 31) * 8;
    float4 p0 = *(const float4*)(px + gcb + c8);
    float4 p1 = *(const float4*)(px + gcb + c8 + 4);
    const ushort* ep = eb + ((size_t)(grp * 16 + s) * Tn) * Hn + gcb + c8;
    ut[s][c8 + 0] = p0.x * bf2f(ep[0]); ut[s][c8 + 1] = p0.y * bf2f(ep[1]);
    ut[s][c8 + 2] = p0.z * bf2f(ep[2]); ut[s][c8 + 3] = p0.w * bf2f(ep[3]);
    ut[s][c8 + 4] = p1.x * bf2f(ep[4]); ut[s][c8 + 5] = p1.y * bf2f(ep[5]);
    ut[s][c8 + 6] = p1.z * bf2f(ep[6]); ut[s][c8 + 7] = p1.w * bf2f(ep[7]);
  }
  __syncthreads();
  // reduce local max
  {
    int s = t >> 5, ch = t & 31;
    float4 x = *(float4*)&ut[s][ch * 8];
    float4 y = *(float4*)&ut[s][ch * 8 + 4];
    float m = fmaxf(fmaxf(fmaxf(x.x, x.y), fmaxf(x.z, x.w)),
                    fmaxf(fmaxf(y.x, y.y), fmaxf(y.z, y.w)));
    for (int o = 1; o <= 16; o <<= 1) m = fmaxf(m, __shfl_xor(m, o, 64));
    if (ch == 0) {
      rqsS[s] = 448.0f * __builtin_amdgcn_rcpf(m);
      moS[s] = m * (1.0f / 448.0f);
    }
  }
  __syncthreads();
  // quantize + ship (step 0)
  const int t_end = lenl[15];
  {
    int s = l15, k0 = (t >> 6) * 32 + quad * 8;
    float vv[8];
#pragma unroll
    for (int j = 0; j < 8; j++) vv[j] = ut[s][k0 + j];
    u64 nv = pack8fp8(vv, rqsS[s]);
    AownL[t] = nv;
    u64* ob = mb + (size_t)((grp * 2 + hh) * 2 + 0) * 520;
    asm volatile("s_waitcnt vmcnt(0)" ::: "memory");
    s64(ob + t, nv);
    if (t < 8) {
      u64 sv = (u64)__float_as_uint(moS[2 * t]) | ((u64)__float_as_uint(moS[2 * t + 1]) << 32);
      s64(ob + 512 + t, sv);
    }
  }
  // prefetches for ts=1
  ushort bp0[4], bp1[4];
  float rmpre = 0.f;
  {
    int n0 = w * 2;
    int j0 = n0 * 16 + l15, j1 = j0 + 16;
#pragma unroll
    for (int r = 0; r < 4; r++) {
      int s = quad * 4 + r;
      const ushort* ebp = eb + ((size_t)(grp * 16 + s) * Tn + 1) * Hn + gcb;
      bp0[r] = ebp[j0]; bp1[r] = ebp[j1];
    }
    if (hh == 0 && t < 16) rmpre = rm[(size_t)(grp * 16 + t) * Tn + 1];
  }

  // ---- recursion ----
  for (int ts = 1; ts < t_end; ts++) {
    __syncthreads();  // B0: AownL/ut stable
    const int pr = (ts + 1) & 1;                 // read parity = (ts-1)&1
    u64* inb = mb + (size_t)((grp * 2 + (1 - hh)) * 2 + pr) * 520;
    u64 pv = a64(inb + t);                       // early poll issue
    u64 pv2 = (t < 8) ? a64(inb + 512 + t) : 0;

    // own-half MFMAs while the poll is in flight
    int n0 = w * 2, n1 = n0 + 1;
    f32x4 ao0 = {0.f, 0.f, 0.f, 0.f}, ao1 = {0.f, 0.f, 0.f, 0.f};
#pragma unroll
    for (int kr = 0; kr < 8; kr++) {
      u64 af = AownL[kr * 64 + lane];
      int ktg = hh * 8 + kr;
      u64 b0 = PfL[(ktg * 16 + n0) * 64 + lane];
      u64 b1 = PfL[(ktg * 16 + n1) * 64 + lane];
      ao0 = __builtin_amdgcn_mfma_f32_16x16x32_fp8_fp8((long)af, (long)b0, ao0, 0, 0, 0);
      ao1 = __builtin_amdgcn_mfma_f32_16x16x32_fp8_fp8((long)af, (long)b1, ao1, 0, 0, 0);
    }
    // finish poll, stage peer frags, re-poison
    while (pv == POISON) pv = a64(inb + t);
    ApeerL[t] = pv;
    s64(inb + t, POISON);
    if (t < 8) {
      while (pv2 == POISON) pv2 = a64(inb + 512 + t);
      mpS[2 * t] = __uint_as_float((uint)pv2);
      mpS[2 * t + 1] = __uint_as_float((uint)(pv2 >> 32));
      s64(inb + 512 + t, POISON);
    }
    __syncthreads();  // B1
    // peer-half MFMAs
    f32x4 ap0 = {0.f, 0.f, 0.f, 0.f}, ap1 = {0.f, 0.f, 0.f, 0.f};
#pragma unroll
    for (int kr = 0; kr < 8; kr++) {
      u64 af = ApeerL[kr * 64 + lane];
      int ktg = (1 - hh) * 8 + kr;
      u64 b0 = PfL[(ktg * 16 + n0) * 64 + lane];
      u64 b1 = PfL[(ktg * 16 + n1) * 64 + lane];
      ap0 = __builtin_amdgcn_mfma_f32_16x16x32_fp8_fp8((long)af, (long)b0, ap0, 0, 0, 0);
      ap1 = __builtin_amdgcn_mfma_f32_16x16x32_fp8_fp8((long)af, (long)b1, ap1, 0, 0, 0);
    }
    // off-path: Cacc (h==0) using OLD moS + fresh mpS
    if (hh == 0 && t < 16 && ts < lenl[t])
      CaccS[t] += logf(fmaxf(moS[t], mpS[t])) + rmpre;
    // epilogue: u = (mo*acc_o + mp*acc_p)/gm * B * rcs
    {
      int j0 = n0 * 16 + l15, j1 = j0 + 16;
      float rc0 = rcsL[j0], rc1 = rcsL[j1];
#pragma unroll
      for (int r = 0; r < 4; r++) {
        int s = quad * 4 + r;
        float mo_ = moS[s], mp_ = mpS[s];
        float rg = __builtin_amdgcn_rcpf(fmaxf(mo_, mp_));
        ut[s][j0] = (mo_ * ao0[r] + mp_ * ap0[r]) * rg * bf2f(bp0[r]) * rc0;
        ut[s][j1] = (mo_ * ao1[r] + mp_ * ap1[r]) * rg * bf2f(bp1[r]) * rc1;
      }
    }
    __syncthreads();  // B2: ut complete; all moS/mpS reads done
    // reduce new local max per seq; update scales for active seqs
    {
      int s = t >> 5, ch = t & 31;
      float4 x = *(float4*)&ut[s][ch * 8];
      float4 y = *(float4*)&ut[s][ch * 8 + 4];
      float m = fmaxf(fmaxf(fmaxf(x.x, x.y), fmaxf(x.z, x.w)),
                      fmaxf(fmaxf(y.x, y.y), fmaxf(y.z, y.w)));
      for (int o = 1; o <= 16; o <<= 1) m = fmaxf(m, __shfl_xor(m, o, 64));
      if (ch == 0) {
        rqsS[s] = 448.0f * __builtin_amdgcn_rcpf(m);
        if (ts < lenl[s]) moS[s] = m * (1.0f / 448.0f);
      }
    }
    __syncthreads();  // B3: scales ready
    // quantize / resend-frozen; ship message
    {
      int s = l15, k0 = (t >> 6) * 32 + quad * 8;
      u64 old = AownL[t];
      u64 nv;
      if (ts < lenl[s]) {
        float vv[8];
#pragma unroll
        for (int j = 0; j < 8; j++) vv[j] = ut[s][k0 + j];
        nv = pack8fp8(vv, rqsS[s]);
      } else {
        nv = old;
      }
      AownL[t] = nv;
      u64* ob = mb + (size_t)((grp * 2 + hh) * 2 + (ts & 1)) * 520;
      asm volatile("s_waitcnt vmcnt(0)" ::: "memory");  // drain this step's poisons first
      s64(ob + t, nv);
      if (t < 8) {
        u64 sv = (u64)__float_as_uint(moS[2 * t]) | ((u64)__float_as_uint(moS[2 * t + 1]) << 32);
        s64(ob + 512 + t, sv);
      }
    }
    // prefetch next B-slice + rm
    {
      int tsn = (ts + 1 < Tn) ? ts + 1 : Tn - 1;
      int j0 = n0 * 16 + l15, j1 = j0 + 16;
#pragma unroll
      for (int r = 0; r < 4; r++) {
        int s = quad * 4 + r;
        const ushort* ebp = eb + ((size_t)(grp * 16 + s) * Tn + tsn) * Hn + gcb;
        bp0[r] = ebp[j0]; bp1[r] = ebp[j1];
      }
      if (hh == 0 && t < 16) rmpre = rm[(size_t)(grp * 16 + t) * Tn + tsn];
    }
  }

  // ---- finale (h==0): poll partner's last message, sum both halves ----
  __syncthreads();
  if (hh == 0) {
    const int pf = (t_end - 1) & 1;
    u64* inb = mb + (size_t)((grp * 2 + 1) * 2 + pf) * 520;
    u64 pv = a64(inb + t);
    while (pv == POISON) pv = a64(inb + t);
    if (t < 8) {
      u64 pv2 = a64(inb + 512 + t);
      while (pv2 == POISON) pv2 = a64(inb + 512 + t);
      mpS[2 * t] = __uint_as_float((uint)pv2);
      mpS[2 * t + 1] = __uint_as_float((uint)(pv2 >> 32));
    }
    u64 ov = AownL[t];
    float po = 0.f, pp = 0.f;
#pragma unroll
    for (int j = 0; j < 8; j++) {
      po += fp8val((uint)(ov >> (8 * j)) & 0xffu);
      pp += fp8val((uint)(pv >> (8 * j)) & 0xffu);
    }
    po += __shfl_xor(po, 16, 64); po += __shfl_xor(po, 32, 64);
    pp += __shfl_xor(pp, 16, 64); pp += __shfl_xor(pp, 32, 64);
    if (lane < 16) { sredO[w][lane] = po; sredP[w][lane] = pp; }
    __syncthreads();
    if (t < 16) {
      float So = 0.f, Sp = 0.f;
#pragma unroll
      for (int ww = 0; ww < 8; ww++) { So += sredO[ww][t]; Sp += sredP[ww][t]; }
      outp[grp * 16 + t] = CaccS[t] + logf(moS[t] * So + mpS[t] * Sp);
    }
  }
}

extern "C" void kernel_launch(void* const* d_in, const int* in_sizes, int n_in,
                              void* d_out, int out_size, void* d_ws, size_t ws_size,
                              hipStream_t stream) {
  const float* seq = (const float*)d_in[0];
  const int* lens = (const int*)d_in[1];
  const float* px = (const float*)d_in[2];
  const float* py = (const float*)d_in[3];
  char* ws = (char*)d_ws;
  ushort* emitb = (ushort*)(ws + 0x0000000);
  float* rm     = (float*)(ws + 0x2000000);
  float* wmat   = (float*)(ws + 0x2020000);
  float* bias   = (float*)(ws + 0x2060000);
  float* cs     = (float*)(ws + 0x2061000);
  float* rcsg   = (float*)(ws + 0x2062000);
  u64* pq       = (u64*)(ws + 0x2070000);
  u64* mb       = (u64*)(ws + 0x20B0000);
  float* outp   = (float*)d_out;

  hipLaunchKernelGGL(k_prep, dim3(512), dim3(128), 0, stream, py, wmat, bias);
  hipLaunchKernelGGL(k_cs, dim3(1), dim3(512), 0, stream, px, cs, rcsg);
  hipLaunchKernelGGL(k_pq, dim3(32), dim3(256), 0, stream, px, cs, pq);
  hipLaunchKernelGGL(k_emit, dim3(8, 512), dim3(256), 0, stream, seq, wmat, bias, emitb);
  hipLaunchKernelGGL(k_rowmax, dim3(NT), dim3(64), 0, stream, emitb, rm);
  hipLaunchKernelGGL(k_bexp, dim3(NT), dim3(256), 0, stream, emitb, rm);
  hipLaunchKernelGGL(k_zero, dim3(33), dim3(256), 0, stream, mb);
  hipLaunchKernelGGL(k_rec2, dim3(8), dim3(512), 0, stream, emitb, rm, pq, px, rcsg, lens, mb, outp);
}